// Round 1
// baseline (2060.460 us; speedup 1.0000x reference)
//
#include <hip/hip_runtime.h>

// Problem constants (match reference: N, M, D = 2048, 2048, 8)
#define PN 2048
#define PM 2048
#define PD 8

// Output layout (flat, fp32, concatenated in return order):
//   cov   : [N*M]        offset 0
//   dx    : [N*M*D]      offset N*M
//   dxx   : [N*M*D]      offset N*M + N*M*D
//   dxdxx : [N*M*D*D]    offset N*M + 2*N*M*D
// Total = 2048*2048*81 = 339,738,624 floats (~1.36 GB) -> write-BW bound.

__global__ __launch_bounds__(256) void rbf_all_kernel(
    const float* __restrict__ x,          // [N, D]
    const float* __restrict__ xx,         // [M, D]
    const float* __restrict__ scale_free, // [D]
    const float* __restrict__ var_free,   // [1]
    float* __restrict__ out)
{
    const unsigned int p = blockIdx.x * 256u + threadIdx.x;  // pair index, < N*M
    const unsigned int n = p >> 11;      // p / M  (M = 2048)
    const unsigned int m = p & 2047u;    // p % M

    // iscale = exp(-scale_free), variance = exp(var_free)
    float is[PD];
#pragma unroll
    for (int d = 0; d < PD; ++d) is[d] = __expf(-scale_free[d]);
    const float variance = __expf(var_free[0]);

    // Vector loads of the two rows (rows are 32 B, 32 B-aligned)
    const float4* x4  = reinterpret_cast<const float4*>(x  + (size_t)n * PD);
    const float4* xx4 = reinterpret_cast<const float4*>(xx + (size_t)m * PD);
    float4 xa = x4[0],  xb = x4[1];
    float4 ya = xx4[0], yb = xx4[1];

    float r[PD];
    r[0] = (xa.x - ya.x) * is[0];
    r[1] = (xa.y - ya.y) * is[1];
    r[2] = (xa.z - ya.z) * is[2];
    r[3] = (xa.w - ya.w) * is[3];
    r[4] = (xb.x - yb.x) * is[4];
    r[5] = (xb.y - yb.y) * is[5];
    r[6] = (xb.z - yb.z) * is[6];
    r[7] = (xb.w - yb.w) * is[7];

    float s = 0.f;
#pragma unroll
    for (int d = 0; d < PD; ++d) s += r[d] * r[d];

    const float cov = __expf(-0.5f * s) * variance;

    float rr[PD], crr[PD];
#pragma unroll
    for (int d = 0; d < PD; ++d) { rr[d] = r[d] * is[d]; crr[d] = cov * rr[d]; }

    // ---- writes ----
    const size_t NM = (size_t)PN * PM;
    float* covp   = out;
    float* dxp    = out + NM;
    float* dxxp   = out + NM + NM * PD;
    float* dxdxxp = out + NM + 2 * NM * PD;

    // cov: one float per pair, coalesced across lanes
    covp[p] = cov;

    // dx = -cov*rr, dxx = +cov*rr  (8 floats each, contiguous per thread)
    {
        float4 v0 = make_float4(-crr[0], -crr[1], -crr[2], -crr[3]);
        float4 v1 = make_float4(-crr[4], -crr[5], -crr[6], -crr[7]);
        float4* d0 = reinterpret_cast<float4*>(dxp + (size_t)p * PD);
        d0[0] = v0; d0[1] = v1;
        float4 w0 = make_float4(crr[0], crr[1], crr[2], crr[3]);
        float4 w1 = make_float4(crr[4], crr[5], crr[6], crr[7]);
        float4* d1 = reinterpret_cast<float4*>(dxxp + (size_t)p * PD);
        d1[0] = w0; d1[1] = w1;
    }

    // dxdxx[i][j] = cov * (-rr[i]*rr[j] + (i==j)*is[i]^2)
    {
        float4* d2 = reinterpret_cast<float4*>(dxdxxp + (size_t)p * (PD * PD));
#pragma unroll
        for (int i = 0; i < PD; ++i) {
            const float a = -crr[i];
            float row[PD];
#pragma unroll
            for (int j = 0; j < PD; ++j) row[j] = a * rr[j];
            row[i] += cov * is[i] * is[i];
            d2[i * 2 + 0] = make_float4(row[0], row[1], row[2], row[3]);
            d2[i * 2 + 1] = make_float4(row[4], row[5], row[6], row[7]);
        }
    }
}

extern "C" void kernel_launch(void* const* d_in, const int* in_sizes, int n_in,
                              void* d_out, int out_size, void* d_ws, size_t ws_size,
                              hipStream_t stream) {
    const float* x  = (const float*)d_in[0];
    const float* xx = (const float*)d_in[1];
    const float* sf = (const float*)d_in[2];
    const float* vf = (const float*)d_in[3];
    float* out = (float*)d_out;

    const int pairs = PN * PM;            // 4,194,304
    const int block = 256;
    const int grid  = pairs / block;      // 16,384
    rbf_all_kernel<<<grid, block, 0, stream>>>(x, xx, sf, vf, out);
}